// Round 1
// baseline (255.105 us; speedup 1.0000x reference)
//
#include <hip/hip_runtime.h>

typedef __attribute__((ext_vector_type(8))) short s16x8;
typedef __attribute__((ext_vector_type(4))) float f32x4;
typedef unsigned short u16;
typedef unsigned int u32;
typedef unsigned long long u64;

__device__ __forceinline__ u16 f2bf(float f) {
  u32 u = __float_as_uint(f);
  u32 r = u + 0x7fffu + ((u >> 16) & 1u);
  return (u16)(r >> 16);
}
__device__ __forceinline__ float bf2f(u16 h) {
  return __uint_as_float(((u32)h) << 16);
}

#define HS_N 3145728   // 4096*768
#define W_N  589824    // 768*768

// ---------------- K0: f32 -> bf16 conversions + bias concat ----------------
__global__ __launch_bounds__(256) void convert_kernel(
    const float* __restrict__ hs, const float* __restrict__ wq, const float* __restrict__ wk,
    const float* __restrict__ wv, const float* __restrict__ wo,
    const float* __restrict__ bq, const float* __restrict__ bk, const float* __restrict__ bv,
    u16* __restrict__ hsb, u16* __restrict__ wqkvb, u16* __restrict__ wob,
    float* __restrict__ biasqkv)
{
  int t = blockIdx.x * 256 + threadIdx.x;
  long i = (long)t * 8;
  const float* src;
  u16* dst;
  if (i < HS_N)              { src = hs + i;                  dst = hsb + i; }
  else if (i < HS_N + W_N)   { src = wq + (i - HS_N);         dst = wqkvb + (i - HS_N); }
  else if (i < HS_N + 2*W_N) { src = wk + (i - HS_N - W_N);   dst = wqkvb + (i - HS_N); }
  else if (i < HS_N + 3*W_N) { src = wv + (i - HS_N - 2*W_N); dst = wqkvb + (i - HS_N); }
  else                       { src = wo + (i - HS_N - 3*W_N); dst = wob + (i - HS_N - 3*W_N); }
  float4 a = ((const float4*)src)[0];
  float4 b = ((const float4*)src)[1];
  uint4 o;
  o.x = (u32)f2bf(a.x) | ((u32)f2bf(a.y) << 16);
  o.y = (u32)f2bf(a.z) | ((u32)f2bf(a.w) << 16);
  o.z = (u32)f2bf(b.x) | ((u32)f2bf(b.y) << 16);
  o.w = (u32)f2bf(b.z) | ((u32)f2bf(b.w) << 16);
  *(uint4*)dst = o;
  if (t < 2304) biasqkv[t] = (t < 768) ? bq[t] : ((t < 1536) ? bk[t - 768] : bv[t - 1536]);
}

// ---------------- GEMM: C = A(bf16 MxK rowmajor) @ Bt(bf16 NxK rowmajor)^T + bias -------
// MODE 0: QKV projection, scatter-write Q[bh][s][d], K[bh][s][d], V^T[bh][d][s] (bf16)
// MODE 1: f32 output [M][768]
template<int MODE, int BM>
__global__ __launch_bounds__(256) void gemm_bt(
    const u16* __restrict__ A, const u16* __restrict__ Bt, const float* __restrict__ bias,
    float* __restrict__ outF, u16* __restrict__ Qb, u16* __restrict__ Kb, u16* __restrict__ Vtb)
{
  constexpr int LDT = 40;            // padded LDS row stride (elements) -> conflict-free-ish
  constexpr int NIT = 768 / 32;      // K iterations
  constexpr int MF  = BM / 32;       // m-frags per wave
  constexpr int ACH = BM * 4 / 256;  // A 16B-chunks per thread

  __shared__ u16 lA[BM * LDT];
  __shared__ u16 lB[128 * LDT];

  const int tid = threadIdx.x;
  const int lane = tid & 63;
  const int w = tid >> 6;
  const int l15 = lane & 15, g = lane >> 4;
  const int mBase = blockIdx.y * BM;
  const int nBase = blockIdx.x * 128;
  const int wr = w >> 1, wc = w & 1;
  const int mW = wr * (BM / 2), nW = wc * 64;

  f32x4 zero = {0.f, 0.f, 0.f, 0.f};
  f32x4 acc[MF][4];
  #pragma unroll
  for (int i = 0; i < MF; i++)
    #pragma unroll
    for (int j = 0; j < 4; j++) acc[i][j] = zero;

  uint4 ra[ACH], rb[2];
  #pragma unroll
  for (int i = 0; i < ACH; i++) {
    int c = tid + i * 256;
    ra[i] = *(const uint4*)(A + (long)(mBase + (c >> 2)) * 768 + (c & 3) * 8);
  }
  #pragma unroll
  for (int i = 0; i < 2; i++) {
    int c = tid + i * 256;
    rb[i] = *(const uint4*)(Bt + (long)(nBase + (c >> 2)) * 768 + (c & 3) * 8);
  }

  for (int kk = 0; kk < NIT; kk++) {
    __syncthreads();
    #pragma unroll
    for (int i = 0; i < ACH; i++) {
      int c = tid + i * 256;
      *(uint4*)&lA[(c >> 2) * LDT + (c & 3) * 8] = ra[i];
    }
    #pragma unroll
    for (int i = 0; i < 2; i++) {
      int c = tid + i * 256;
      *(uint4*)&lB[(c >> 2) * LDT + (c & 3) * 8] = rb[i];
    }
    __syncthreads();
    if (kk + 1 < NIT) {
      int k0 = (kk + 1) * 32;
      #pragma unroll
      for (int i = 0; i < ACH; i++) {
        int c = tid + i * 256;
        ra[i] = *(const uint4*)(A + (long)(mBase + (c >> 2)) * 768 + k0 + (c & 3) * 8);
      }
      #pragma unroll
      for (int i = 0; i < 2; i++) {
        int c = tid + i * 256;
        rb[i] = *(const uint4*)(Bt + (long)(nBase + (c >> 2)) * 768 + k0 + (c & 3) * 8);
      }
    }
    s16x8 bfr[4];
    #pragma unroll
    for (int ni = 0; ni < 4; ni++)
      bfr[ni] = *(const s16x8*)&lB[(nW + ni * 16 + l15) * LDT + g * 8];
    #pragma unroll
    for (int mi = 0; mi < MF; mi++) {
      s16x8 afr = *(const s16x8*)&lA[(mW + mi * 16 + l15) * LDT + g * 8];
      #pragma unroll
      for (int ni = 0; ni < 4; ni++)
        acc[mi][ni] = __builtin_amdgcn_mfma_f32_16x16x32_bf16(afr, bfr[ni], acc[mi][ni], 0, 0, 0);
    }
  }

  #pragma unroll
  for (int mi = 0; mi < MF; mi++) {
    #pragma unroll
    for (int ni = 0; ni < 4; ni++) {
      int n = nBase + nW + ni * 16 + l15;
      int m0 = mBase + mW + mi * 16 + g * 4;
      float b = bias[n];
      float v0 = acc[mi][ni][0] + b;
      float v1 = acc[mi][ni][1] + b;
      float v2 = acc[mi][ni][2] + b;
      float v3 = acc[mi][ni][3] + b;
      if constexpr (MODE == 1) {
        outF[(long)m0 * 768 + n] = v0;
        outF[(long)(m0 + 1) * 768 + n] = v1;
        outF[(long)(m0 + 2) * 768 + n] = v2;
        outF[(long)(m0 + 3) * 768 + n] = v3;
      } else {
        int typ = n / 768;
        int hn = n - typ * 768;
        int h = hn >> 6, d = hn & 63;
        int b_ = m0 >> 10, s0 = m0 & 1023;
        long bh = b_ * 12 + h;
        if (typ == 2) {
          u64 pk = (u64)((u32)f2bf(v0) | ((u32)f2bf(v1) << 16)) |
                   (((u64)((u32)f2bf(v2) | ((u32)f2bf(v3) << 16))) << 32);
          *(u64*)(Vtb + (bh << 16) + (d << 10) + s0) = pk;
        } else {
          u16* dst = (typ == 0 ? Qb : Kb) + (bh << 16) + ((long)s0 << 6) + d;
          dst[0]   = f2bf(v0);
          dst[64]  = f2bf(v1);
          dst[128] = f2bf(v2);
          dst[192] = f2bf(v3);
        }
      }
    }
  }
}

// ---------------- K2: build qAe/kAe extended features + beta ----------------
// qAe[row][0:16)=0.25*qA, [16:80)=0.25e-3*q, [80:128)=0
// kAe[row][0:16)=kA,      [16:80)=1e-3*k,    [80:128)=0
// beta[row] = -0.125*(|kA|^2 + 1e-6|k|^2) + mask[b][t]
__global__ __launch_bounds__(256) void qk_ext_kernel(
    const u16* __restrict__ Qb, const u16* __restrict__ Kb, const float* __restrict__ Am,
    const float* __restrict__ mask, u16* __restrict__ qAe, u16* __restrict__ kAe,
    float* __restrict__ beta2)
{
  const bool isK = blockIdx.x >= 192;
  const int rb = blockIdx.x * 256 - (isK ? 49152 : 0);
  const int h = (rb >> 10) % 12;              // uniform (blockIdx-derived)
  const int row = rb + threadIdx.x;           // bh*1024 + s
  const int bh = row >> 10;
  const int s = row & 1023;
  const int b_ = bh / 12;

  const u16* src = (isK ? Kb : Qb) + ((long)row << 6);
  union { uint4 v4[8]; u32 u[32]; } c;
  #pragma unroll
  for (int i = 0; i < 8; i++) c.v4[i] = ((const uint4*)src)[i];

  const float* Ah = Am + h * 1024;
  float acc[16];
  #pragma unroll
  for (int r = 0; r < 16; r++) acc[r] = 0.f;
  float s2 = 0.f;
  #pragma unroll
  for (int d = 0; d < 64; d++) {
    u32 wd = c.u[d >> 1];
    float qd = bf2f((u16)((d & 1) ? (wd >> 16) : (wd & 0xffffu)));
    s2 += qd * qd;
    #pragma unroll
    for (int r = 0; r < 16; r++) acc[r] += qd * Ah[d * 16 + r];
  }

  union { u16 us[128]; uint4 v4[16]; } o;
  const float sA = isK ? 1.0f : 0.25f;
  const float sQ = isK ? 1e-3f : 0.25e-3f;
  #pragma unroll
  for (int r = 0; r < 16; r++) o.us[r] = f2bf(acc[r] * sA);
  #pragma unroll
  for (int d = 0; d < 64; d++) {
    u32 wd = c.u[d >> 1];
    float qd = bf2f((u16)((d & 1) ? (wd >> 16) : (wd & 0xffffu)));
    o.us[16 + d] = f2bf(qd * sQ);
  }
  #pragma unroll
  for (int j = 80; j < 128; j++) o.us[j] = 0;

  u16* dst = (isK ? kAe : qAe) + ((long)row << 7);
  #pragma unroll
  for (int i = 0; i < 16; i++) ((uint4*)dst)[i] = o.v4[i];

  if (isK) {
    float kk = 1e-6f * s2;
    #pragma unroll
    for (int r = 0; r < 16; r++) kk += acc[r] * acc[r];
    beta2[row] = -0.125f * kk + mask[(b_ << 10) + s];
  }
}

// ---------------- K3: attention (no online-softmax needed; scores bounded) -------------
// grid: bh(48) x qtile(16); block 128 = 2 waves; wave owns 32 q rows; barrier-free.
__global__ __launch_bounds__(128) void attn_kernel(
    const u16* __restrict__ qAe, const u16* __restrict__ kAe, const u16* __restrict__ Vtb,
    const float* __restrict__ beta2, u16* __restrict__ ctxb)
{
  const int tid = threadIdx.x;
  const int lane = tid & 63;
  const int w = tid >> 6;
  const int l15 = lane & 15, g = lane >> 4;
  const int bh = blockIdx.x >> 4;
  const int qt = blockIdx.x & 15;
  const int q0 = qt * 64 + w * 32;

  __shared__ char Plds[2][8192];   // per-wave P buffer: 32 q x 128 t bf16, XOR-swizzled
  char* Pw = Plds[w];

  // hoist qAe B-fragments for the whole kernel (q rows fixed)
  s16x8 bq[2][4];
  const u16* qbase = qAe + ((long)(bh * 1024 + q0) << 7);
  #pragma unroll
  for (int qf = 0; qf < 2; qf++)
    #pragma unroll
    for (int ks = 0; ks < 4; ks++)
      bq[qf][ks] = *(const s16x8*)(qbase + ((qf * 16 + l15) << 7) + ks * 32 + g * 8);

  f32x4 zero = {0.f, 0.f, 0.f, 0.f};
  f32x4 cacc[2][4];
  #pragma unroll
  for (int a = 0; a < 2; a++)
    #pragma unroll
    for (int b = 0; b < 4; b++) cacc[a][b] = zero;
  float rsum[2] = {0.f, 0.f};

  const u16* kbase = kAe + ((long)bh << 17);
  const u16* vbase = Vtb + ((long)bh << 16);
  const float* betab = beta2 + (bh << 10);

  for (int t0 = 0; t0 < 1024; t0 += 128) {
    // phase A: S^T = kAe @ qAe^T ; P = exp(S + beta) -> LDS (swizzled)
    #pragma unroll
    for (int tf = 0; tf < 8; tf++) {
      f32x4 sacc[2];
      sacc[0] = zero; sacc[1] = zero;
      #pragma unroll
      for (int ks = 0; ks < 4; ks++) {
        s16x8 ak = *(const s16x8*)(kbase + ((long)(t0 + tf * 16 + l15) << 7) + ks * 32 + g * 8);
        sacc[0] = __builtin_amdgcn_mfma_f32_16x16x32_bf16(ak, bq[0][ks], sacc[0], 0, 0, 0);
        sacc[1] = __builtin_amdgcn_mfma_f32_16x16x32_bf16(ak, bq[1][ks], sacc[1], 0, 0, 0);
      }
      f32x4 bb = *(const f32x4*)(betab + t0 + tf * 16 + g * 4);
      #pragma unroll
      for (int qf = 0; qf < 2; qf++) {
        u16 h0 = f2bf(__expf(sacc[qf][0] + bb[0]));
        u16 h1 = f2bf(__expf(sacc[qf][1] + bb[1]));
        u16 h2 = f2bf(__expf(sacc[qf][2] + bb[2]));
        u16 h3 = f2bf(__expf(sacc[qf][3] + bb[3]));
        rsum[qf] += bf2f(h0) + bf2f(h1) + bf2f(h2) + bf2f(h3);
        int q = qf * 16 + l15;
        u32 off = (u32)((q << 8) + (tf << 5) + (g << 3));
        off ^= (u32)((q & 7) << 4);
        u64 pk = (u64)((u32)h0 | ((u32)h1 << 16)) |
                 (((u64)((u32)h2 | ((u32)h3 << 16))) << 32);
        *(u64*)(Pw + off) = pk;
      }
    }
    // phase B: ctx += P @ V  (A-frags = own P from LDS, B-frags = V^T from global/L2)
    #pragma unroll
    for (int ks = 0; ks < 4; ks++) {
      s16x8 bv[4];
      #pragma unroll
      for (int df = 0; df < 4; df++)
        bv[df] = *(const s16x8*)(vbase + ((df * 16 + l15) << 10) + t0 + ks * 32 + g * 8);
      #pragma unroll
      for (int qf = 0; qf < 2; qf++) {
        int q = qf * 16 + l15;
        u32 off = (u32)((q << 8) + (ks << 6) + (g << 4));
        off ^= (u32)((q & 7) << 4);
        s16x8 ap = *(const s16x8*)(Pw + off);
        #pragma unroll
        for (int df = 0; df < 4; df++)
          cacc[qf][df] = __builtin_amdgcn_mfma_f32_16x16x32_bf16(ap, bv[df], cacc[qf][df], 0, 0, 0);
      }
    }
  }

  #pragma unroll
  for (int qf = 0; qf < 2; qf++) {
    rsum[qf] += __shfl_xor(rsum[qf], 16);
    rsum[qf] += __shfl_xor(rsum[qf], 32);
  }

  const int b_ = bh / 12, h = bh % 12;
  #pragma unroll
  for (int qf = 0; qf < 2; qf++) {
    #pragma unroll
    for (int j = 0; j < 4; j++) {
      float rs = __shfl(rsum[qf], g * 4 + j);
      float rinv = 1.0f / rs;
      int qg = q0 + qf * 16 + g * 4 + j;
      long base = ((long)(b_ * 1024 + qg)) * 768 + h * 64;
      #pragma unroll
      for (int df = 0; df < 4; df++)
        ctxb[base + df * 16 + l15] = f2bf(cacc[qf][df][j] * rinv);
    }
  }
}

// ---------------- launcher ----------------
extern "C" void kernel_launch(void* const* d_in, const int* in_sizes, int n_in,
                              void* d_out, int out_size, void* d_ws, size_t ws_size,
                              hipStream_t stream)
{
  (void)in_sizes; (void)n_in; (void)out_size; (void)ws_size;
  const float* hs   = (const float*)d_in[0];
  const float* mask = (const float*)d_in[1];
  const float* Wq   = (const float*)d_in[2];
  const float* bq   = (const float*)d_in[3];
  const float* Wk   = (const float*)d_in[4];
  const float* bk   = (const float*)d_in[5];
  const float* Wv   = (const float*)d_in[6];
  const float* bv   = (const float*)d_in[7];
  const float* Wo   = (const float*)d_in[8];
  const float* bo   = (const float*)d_in[9];
  const float* Am   = (const float*)d_in[10];
  float* out = (float*)d_out;

  char* p = (char*)d_ws;
  u16* hsb      = (u16*)p;   p += 6291456;
  u16* wqkvb    = (u16*)p;   p += 3538944;
  u16* wob      = (u16*)p;   p += 1179648;
  float* biasqkv= (float*)p; p += 9216;
  u16* Qb       = (u16*)p;   p += 6291456;
  u16* Kb       = (u16*)p;   p += 6291456;
  u16* Vtb      = (u16*)p;   p += 6291456;
  u16* qAeb     = (u16*)p;   p += 12582912;
  u16* kAeb     = (u16*)p;   p += 12582912;
  float* beta2  = (float*)p; p += 196608;
  u16* ctxb     = (u16*)p;   p += 6291456;

  convert_kernel<<<2688, 256, 0, stream>>>(hs, Wq, Wk, Wv, Wo, bq, bk, bv,
                                           hsb, wqkvb, wob, biasqkv);
  gemm_bt<0, 128><<<dim3(18, 32), 256, 0, stream>>>(hsb, wqkvb, biasqkv,
                                                    nullptr, Qb, Kb, Vtb);
  qk_ext_kernel<<<384, 256, 0, stream>>>(Qb, Kb, Am, mask, qAeb, kAeb, beta2);
  attn_kernel<<<768, 128, 0, stream>>>(qAeb, kAeb, Vtb, beta2, ctxb);
  gemm_bt<1, 64><<<dim3(6, 64), 256, 0, stream>>>(ctxb, wob, bo, out,
                                                  nullptr, nullptr, nullptr);
}

// Round 2
// 229.126 us; speedup vs baseline: 1.1134x; 1.1134x over previous
//
#include <hip/hip_runtime.h>

typedef __attribute__((ext_vector_type(8))) short s16x8;
typedef __attribute__((ext_vector_type(4))) float f32x4;
typedef unsigned short u16;
typedef unsigned int u32;
typedef unsigned long long u64;

__device__ __forceinline__ u16 f2bf(float f) {
  u32 u = __float_as_uint(f);
  u32 r = u + 0x7fffu + ((u >> 16) & 1u);
  return (u16)(r >> 16);
}
__device__ __forceinline__ float bf2f(u16 h) {
  return __uint_as_float(((u32)h) << 16);
}

#define HS_N 3145728   // 4096*768
#define W_N  589824    // 768*768

// ---------------- K0: f32 -> bf16 conversions + bias concat ----------------
__global__ __launch_bounds__(256) void convert_kernel(
    const float* __restrict__ hs, const float* __restrict__ wq, const float* __restrict__ wk,
    const float* __restrict__ wv, const float* __restrict__ wo,
    const float* __restrict__ bq, const float* __restrict__ bk, const float* __restrict__ bv,
    u16* __restrict__ hsb, u16* __restrict__ wqkvb, u16* __restrict__ wob,
    float* __restrict__ biasqkv)
{
  int t = blockIdx.x * 256 + threadIdx.x;
  long i = (long)t * 8;
  const float* src;
  u16* dst;
  if (i < HS_N)              { src = hs + i;                  dst = hsb + i; }
  else if (i < HS_N + W_N)   { src = wq + (i - HS_N);         dst = wqkvb + (i - HS_N); }
  else if (i < HS_N + 2*W_N) { src = wk + (i - HS_N - W_N);   dst = wqkvb + (i - HS_N); }
  else if (i < HS_N + 3*W_N) { src = wv + (i - HS_N - 2*W_N); dst = wqkvb + (i - HS_N); }
  else                       { src = wo + (i - HS_N - 3*W_N); dst = wob + (i - HS_N - 3*W_N); }
  float4 a = ((const float4*)src)[0];
  float4 b = ((const float4*)src)[1];
  uint4 o;
  o.x = (u32)f2bf(a.x) | ((u32)f2bf(a.y) << 16);
  o.y = (u32)f2bf(a.z) | ((u32)f2bf(a.w) << 16);
  o.z = (u32)f2bf(b.x) | ((u32)f2bf(b.y) << 16);
  o.w = (u32)f2bf(b.z) | ((u32)f2bf(b.w) << 16);
  *(uint4*)dst = o;
  if (t < 2304) biasqkv[t] = (t < 768) ? bq[t] : ((t < 1536) ? bk[t - 768] : bv[t - 1536]);
}

// ---------------- GEMM: C = A(bf16 MxK rowmajor) @ Bt(bf16 NxK rowmajor)^T + bias -------
// MODE 0: QKV projection, scatter-write Q[bh][s][d], K[bh][s][d], V^T[bh][d][s] (bf16)
// MODE 1: f32 output [M][768]
template<int MODE, int BM>
__global__ __launch_bounds__(256) void gemm_bt(
    const u16* __restrict__ A, const u16* __restrict__ Bt, const float* __restrict__ bias,
    float* __restrict__ outF, u16* __restrict__ Qb, u16* __restrict__ Kb, u16* __restrict__ Vtb)
{
  constexpr int LDT = 40;            // padded LDS row stride (elements) -> conflict-free-ish
  constexpr int NIT = 768 / 32;      // K iterations
  constexpr int MF  = BM / 32;       // m-frags per wave
  constexpr int ACH = BM * 4 / 256;  // A 16B-chunks per thread

  __shared__ u16 lA[BM * LDT];
  __shared__ u16 lB[128 * LDT];

  const int tid = threadIdx.x;
  const int lane = tid & 63;
  const int w = tid >> 6;
  const int l15 = lane & 15, g = lane >> 4;
  const int mBase = blockIdx.y * BM;
  const int nBase = blockIdx.x * 128;
  const int wr = w >> 1, wc = w & 1;
  const int mW = wr * (BM / 2), nW = wc * 64;

  f32x4 zero = {0.f, 0.f, 0.f, 0.f};
  f32x4 acc[MF][4];
  #pragma unroll
  for (int i = 0; i < MF; i++)
    #pragma unroll
    for (int j = 0; j < 4; j++) acc[i][j] = zero;

  uint4 ra[ACH], rb[2];
  #pragma unroll
  for (int i = 0; i < ACH; i++) {
    int c = tid + i * 256;
    ra[i] = *(const uint4*)(A + (long)(mBase + (c >> 2)) * 768 + (c & 3) * 8);
  }
  #pragma unroll
  for (int i = 0; i < 2; i++) {
    int c = tid + i * 256;
    rb[i] = *(const uint4*)(Bt + (long)(nBase + (c >> 2)) * 768 + (c & 3) * 8);
  }

  for (int kk = 0; kk < NIT; kk++) {
    __syncthreads();
    #pragma unroll
    for (int i = 0; i < ACH; i++) {
      int c = tid + i * 256;
      *(uint4*)&lA[(c >> 2) * LDT + (c & 3) * 8] = ra[i];
    }
    #pragma unroll
    for (int i = 0; i < 2; i++) {
      int c = tid + i * 256;
      *(uint4*)&lB[(c >> 2) * LDT + (c & 3) * 8] = rb[i];
    }
    __syncthreads();
    if (kk + 1 < NIT) {
      int k0 = (kk + 1) * 32;
      #pragma unroll
      for (int i = 0; i < ACH; i++) {
        int c = tid + i * 256;
        ra[i] = *(const uint4*)(A + (long)(mBase + (c >> 2)) * 768 + k0 + (c & 3) * 8);
      }
      #pragma unroll
      for (int i = 0; i < 2; i++) {
        int c = tid + i * 256;
        rb[i] = *(const uint4*)(Bt + (long)(nBase + (c >> 2)) * 768 + k0 + (c & 3) * 8);
      }
    }
    s16x8 bfr[4];
    #pragma unroll
    for (int ni = 0; ni < 4; ni++)
      bfr[ni] = *(const s16x8*)&lB[(nW + ni * 16 + l15) * LDT + g * 8];
    #pragma unroll
    for (int mi = 0; mi < MF; mi++) {
      s16x8 afr = *(const s16x8*)&lA[(mW + mi * 16 + l15) * LDT + g * 8];
      #pragma unroll
      for (int ni = 0; ni < 4; ni++)
        acc[mi][ni] = __builtin_amdgcn_mfma_f32_16x16x32_bf16(afr, bfr[ni], acc[mi][ni], 0, 0, 0);
    }
  }

  #pragma unroll
  for (int mi = 0; mi < MF; mi++) {
    #pragma unroll
    for (int ni = 0; ni < 4; ni++) {
      int n = nBase + nW + ni * 16 + l15;
      int m0 = mBase + mW + mi * 16 + g * 4;
      float b = bias[n];
      float v0 = acc[mi][ni][0] + b;
      float v1 = acc[mi][ni][1] + b;
      float v2 = acc[mi][ni][2] + b;
      float v3 = acc[mi][ni][3] + b;
      if constexpr (MODE == 1) {
        outF[(long)m0 * 768 + n] = v0;
        outF[(long)(m0 + 1) * 768 + n] = v1;
        outF[(long)(m0 + 2) * 768 + n] = v2;
        outF[(long)(m0 + 3) * 768 + n] = v3;
      } else {
        int typ = n / 768;
        int hn = n - typ * 768;
        int h = hn >> 6, d = hn & 63;
        int b_ = m0 >> 10, s0 = m0 & 1023;
        long bh = b_ * 12 + h;
        if (typ == 2) {
          u64 pk = (u64)((u32)f2bf(v0) | ((u32)f2bf(v1) << 16)) |
                   (((u64)((u32)f2bf(v2) | ((u32)f2bf(v3) << 16))) << 32);
          *(u64*)(Vtb + (bh << 16) + (d << 10) + s0) = pk;
        } else {
          u16* dst = (typ == 0 ? Qb : Kb) + (bh << 16) + ((long)s0 << 6) + d;
          dst[0]   = f2bf(v0);
          dst[64]  = f2bf(v1);
          dst[128] = f2bf(v2);
          dst[192] = f2bf(v3);
        }
      }
    }
  }
}

// ---------------- K2: build qAe/kAe extended features + beta ----------------
__global__ __launch_bounds__(256) void qk_ext_kernel(
    const u16* __restrict__ Qb, const u16* __restrict__ Kb, const float* __restrict__ Am,
    const float* __restrict__ mask, u16* __restrict__ qAe, u16* __restrict__ kAe,
    float* __restrict__ beta2)
{
  const bool isK = blockIdx.x >= 192;
  const int rb = blockIdx.x * 256 - (isK ? 49152 : 0);
  const int h = (rb >> 10) % 12;              // uniform (blockIdx-derived)
  const int row = rb + threadIdx.x;           // bh*1024 + s
  const int bh = row >> 10;
  const int s = row & 1023;
  const int b_ = bh / 12;

  const u16* src = (isK ? Kb : Qb) + ((long)row << 6);
  union { uint4 v4[8]; u32 u[32]; } c;
  #pragma unroll
  for (int i = 0; i < 8; i++) c.v4[i] = ((const uint4*)src)[i];

  const float* Ah = Am + h * 1024;
  float acc[16];
  #pragma unroll
  for (int r = 0; r < 16; r++) acc[r] = 0.f;
  float s2 = 0.f;
  #pragma unroll
  for (int d = 0; d < 64; d++) {
    u32 wd = c.u[d >> 1];
    float qd = bf2f((u16)((d & 1) ? (wd >> 16) : (wd & 0xffffu)));
    s2 += qd * qd;
    #pragma unroll
    for (int r = 0; r < 16; r++) acc[r] += qd * Ah[d * 16 + r];
  }

  union { u16 us[128]; uint4 v4[16]; } o;
  const float sA = isK ? 1.0f : 0.25f;
  const float sQ = isK ? 1e-3f : 0.25e-3f;
  #pragma unroll
  for (int r = 0; r < 16; r++) o.us[r] = f2bf(acc[r] * sA);
  #pragma unroll
  for (int d = 0; d < 64; d++) {
    u32 wd = c.u[d >> 1];
    float qd = bf2f((u16)((d & 1) ? (wd >> 16) : (wd & 0xffffu)));
    o.us[16 + d] = f2bf(qd * sQ);
  }
  #pragma unroll
  for (int j = 80; j < 128; j++) o.us[j] = 0;

  u16* dst = (isK ? kAe : qAe) + ((long)row << 7);
  #pragma unroll
  for (int i = 0; i < 16; i++) ((uint4*)dst)[i] = o.v4[i];

  if (isK) {
    float kk = 1e-6f * s2;
    #pragma unroll
    for (int r = 0; r < 16; r++) kk += acc[r] * acc[r];
    beta2[row] = -0.125f * kk + mask[(b_ << 10) + s];
  }
}

// ---------------- K3: attention, t-split across 4 waves ----------------
// grid: 1536 blocks (48 bh x 32 qtiles of 32 rows), XCD-swizzled; block 256 = 4 waves.
// Each wave: same 32 q rows, t-range [w*256, w*256+256). Partial ctx/rsum combined in LDS.
__global__ __launch_bounds__(256, 4) void attn_kernel(
    const u16* __restrict__ qAe, const u16* __restrict__ kAe, const u16* __restrict__ Vtb,
    const float* __restrict__ beta2, u16* __restrict__ ctxb)
{
  const int tid = threadIdx.x;
  const int lane = tid & 63;
  const int w = tid >> 6;
  const int l15 = lane & 15, g = lane >> 4;
  // XCD-aware swizzle: 1536 blocks = 8 XCDs * 192 -> each XCD covers 6 consecutive bh
  const int wid = (blockIdx.x & 7) * 192 + (blockIdx.x >> 3);
  const int bh = wid >> 5;
  const int qt = wid & 31;
  const int q0 = qt * 32;

  __shared__ __align__(16) union {
    char P[4][8192];          // per-wave P: 32q x 128t bf16, XOR-swizzled
    float red[4][32][68];     // cross-wave ctx reduce (stride 68 -> 2-way banks = free)
  } sm;
  __shared__ float rsLds[4][32];
  char* Pw = sm.P[w];

  // hoist qAe B-fragments for the whole kernel (q rows fixed per block)
  s16x8 bq[2][4];
  const u16* qbase = qAe + ((long)(bh * 1024 + q0) << 7);
  #pragma unroll
  for (int qf = 0; qf < 2; qf++)
    #pragma unroll
    for (int ks = 0; ks < 4; ks++)
      bq[qf][ks] = *(const s16x8*)(qbase + ((qf * 16 + l15) << 7) + ks * 32 + g * 8);

  f32x4 zero = {0.f, 0.f, 0.f, 0.f};
  f32x4 cacc[2][4];
  #pragma unroll
  for (int a = 0; a < 2; a++)
    #pragma unroll
    for (int b = 0; b < 4; b++) cacc[a][b] = zero;
  float rsum[2] = {0.f, 0.f};

  const u16* kbase = kAe + ((long)bh << 17);
  const u16* vbase = Vtb + ((long)bh << 16);
  const float* betab = beta2 + (bh << 10);

  #pragma unroll
  for (int tt = 0; tt < 2; tt++) {
    const int t0 = w * 256 + tt * 128;
    // phase A: S^T = kAe @ qAe^T ; P = exp(S + beta) -> LDS (swizzled)
    #pragma unroll
    for (int tf = 0; tf < 8; tf++) {
      f32x4 sacc[2];
      sacc[0] = zero; sacc[1] = zero;
      #pragma unroll
      for (int ks = 0; ks < 4; ks++) {
        s16x8 ak = *(const s16x8*)(kbase + ((long)(t0 + tf * 16 + l15) << 7) + ks * 32 + g * 8);
        sacc[0] = __builtin_amdgcn_mfma_f32_16x16x32_bf16(ak, bq[0][ks], sacc[0], 0, 0, 0);
        sacc[1] = __builtin_amdgcn_mfma_f32_16x16x32_bf16(ak, bq[1][ks], sacc[1], 0, 0, 0);
      }
      f32x4 bb = *(const f32x4*)(betab + t0 + tf * 16 + g * 4);
      #pragma unroll
      for (int qf = 0; qf < 2; qf++) {
        u16 h0 = f2bf(__expf(sacc[qf][0] + bb[0]));
        u16 h1 = f2bf(__expf(sacc[qf][1] + bb[1]));
        u16 h2 = f2bf(__expf(sacc[qf][2] + bb[2]));
        u16 h3 = f2bf(__expf(sacc[qf][3] + bb[3]));
        rsum[qf] += bf2f(h0) + bf2f(h1) + bf2f(h2) + bf2f(h3);
        int q = qf * 16 + l15;
        u32 off = (u32)((q << 8) + (tf << 5) + (g << 3));
        off ^= (u32)((q & 7) << 4);
        u64 pk = (u64)((u32)h0 | ((u32)h1 << 16)) |
                 (((u64)((u32)h2 | ((u32)h3 << 16))) << 32);
        *(u64*)(Pw + off) = pk;
      }
    }
    // phase B: ctx += P @ V  (A-frags = own P from LDS, B-frags = V^T from global/L2)
    #pragma unroll
    for (int ks = 0; ks < 4; ks++) {
      s16x8 bv[4];
      #pragma unroll
      for (int df = 0; df < 4; df++)
        bv[df] = *(const s16x8*)(vbase + ((df * 16 + l15) << 10) + t0 + ks * 32 + g * 8);
      #pragma unroll
      for (int qf = 0; qf < 2; qf++) {
        int q = qf * 16 + l15;
        u32 off = (u32)((q << 8) + (ks << 6) + (g << 4));
        off ^= (u32)((q & 7) << 4);
        s16x8 ap = *(const s16x8*)(Pw + off);
        #pragma unroll
        for (int df = 0; df < 4; df++)
          cacc[qf][df] = __builtin_amdgcn_mfma_f32_16x16x32_bf16(ap, bv[df], cacc[qf][df], 0, 0, 0);
      }
    }
  }

  // wave-local rsum reduce (sum over g groups); then publish per-wave row sums
  #pragma unroll
  for (int qf = 0; qf < 2; qf++) {
    rsum[qf] += __shfl_xor(rsum[qf], 16);
    rsum[qf] += __shfl_xor(rsum[qf], 32);
  }
  if (g == 0) {
    rsLds[w][l15] = rsum[0];
    rsLds[w][16 + l15] = rsum[1];
  }

  __syncthreads();   // all P reads done; rsLds published

  // write per-wave partial ctx into reduce buffer (overwrites P region)
  #pragma unroll
  for (int qf = 0; qf < 2; qf++)
    #pragma unroll
    for (int df = 0; df < 4; df++)
      #pragma unroll
      for (int j = 0; j < 4; j++)
        sm.red[w][qf * 16 + g * 4 + j][df * 16 + l15] = cacc[qf][df][j];

  __syncthreads();

  // final cross-wave reduce: thread -> (q = tid>>3, 8 d's at (tid&7)*8)
  const int q = tid >> 3;
  const int d0 = (tid & 7) * 8;
  float rtot = rsLds[0][q] + rsLds[1][q] + rsLds[2][q] + rsLds[3][q];
  float rinv = 1.0f / rtot;
  float a8[8] = {0.f, 0.f, 0.f, 0.f, 0.f, 0.f, 0.f, 0.f};
  #pragma unroll
  for (int ww = 0; ww < 4; ww++) {
    f32x4 v0 = *(const f32x4*)&sm.red[ww][q][d0];
    f32x4 v1 = *(const f32x4*)&sm.red[ww][q][d0 + 4];
    a8[0] += v0[0]; a8[1] += v0[1]; a8[2] += v0[2]; a8[3] += v0[3];
    a8[4] += v1[0]; a8[5] += v1[1]; a8[6] += v1[2]; a8[7] += v1[3];
  }
  const int b_ = bh / 12, h = bh % 12;
  long base = ((long)(b_ * 1024 + q0 + q)) * 768 + h * 64 + d0;
  uint4 o;
  o.x = (u32)f2bf(a8[0] * rinv) | ((u32)f2bf(a8[1] * rinv) << 16);
  o.y = (u32)f2bf(a8[2] * rinv) | ((u32)f2bf(a8[3] * rinv) << 16);
  o.z = (u32)f2bf(a8[4] * rinv) | ((u32)f2bf(a8[5] * rinv) << 16);
  o.w = (u32)f2bf(a8[6] * rinv) | ((u32)f2bf(a8[7] * rinv) << 16);
  *(uint4*)(ctxb + base) = o;
}

// ---------------- launcher ----------------
extern "C" void kernel_launch(void* const* d_in, const int* in_sizes, int n_in,
                              void* d_out, int out_size, void* d_ws, size_t ws_size,
                              hipStream_t stream)
{
  (void)in_sizes; (void)n_in; (void)out_size; (void)ws_size;
  const float* hs   = (const float*)d_in[0];
  const float* mask = (const float*)d_in[1];
  const float* Wq   = (const float*)d_in[2];
  const float* bq   = (const float*)d_in[3];
  const float* Wk   = (const float*)d_in[4];
  const float* bk   = (const float*)d_in[5];
  const float* Wv   = (const float*)d_in[6];
  const float* bv   = (const float*)d_in[7];
  const float* Wo   = (const float*)d_in[8];
  const float* bo   = (const float*)d_in[9];
  const float* Am   = (const float*)d_in[10];
  float* out = (float*)d_out;

  char* p = (char*)d_ws;
  u16* hsb      = (u16*)p;   p += 6291456;
  u16* wqkvb    = (u16*)p;   p += 3538944;
  u16* wob      = (u16*)p;   p += 1179648;
  float* biasqkv= (float*)p; p += 9216;
  u16* Qb       = (u16*)p;   p += 6291456;
  u16* Kb       = (u16*)p;   p += 6291456;
  u16* Vtb      = (u16*)p;   p += 6291456;
  u16* qAeb     = (u16*)p;   p += 12582912;
  u16* kAeb     = (u16*)p;   p += 12582912;
  float* beta2  = (float*)p; p += 196608;
  u16* ctxb     = (u16*)p;   p += 6291456;

  convert_kernel<<<2688, 256, 0, stream>>>(hs, Wq, Wk, Wv, Wo, bq, bk, bv,
                                           hsb, wqkvb, wob, biasqkv);
  gemm_bt<0, 128><<<dim3(18, 32), 256, 0, stream>>>(hsb, wqkvb, biasqkv,
                                                    nullptr, Qb, Kb, Vtb);
  qk_ext_kernel<<<384, 256, 0, stream>>>(Qb, Kb, Am, mask, qAeb, kAeb, beta2);
  attn_kernel<<<1536, 256, 0, stream>>>(qAeb, kAeb, Vtb, beta2, ctxb);
  gemm_bt<1, 64><<<dim3(6, 64), 256, 0, stream>>>(ctxb, wob, bo, out,
                                                  nullptr, nullptr, nullptr);
}

// Round 3
// 186.386 us; speedup vs baseline: 1.3687x; 1.2293x over previous
//
#include <hip/hip_runtime.h>

typedef __attribute__((ext_vector_type(8))) short s16x8;
typedef __attribute__((ext_vector_type(4))) float f32x4;
typedef __attribute__((ext_vector_type(4))) unsigned int u32x4;
typedef unsigned short u16;
typedef unsigned int u32;
typedef unsigned long long u64;

__device__ __forceinline__ u16 f2bf(float f) {
  u32 u = __float_as_uint(f);
  u32 r = u + 0x7fffu + ((u >> 16) & 1u);
  return (u16)(r >> 16);
}
__device__ __forceinline__ float bf2f(u16 h) {
  return __uint_as_float(((u32)h) << 16);
}

typedef __attribute__((address_space(3))) char lds_char_t;
typedef __attribute__((address_space(1))) const char glb_char_t;
__device__ __forceinline__ void gl2lds16(const void* g, void* l) {
  __builtin_amdgcn_global_load_lds((glb_char_t*)g, (lds_char_t*)l, 16, 0, 0);
}

#define HS_N 3145728   // 4096*768
#define W_N  589824    // 768*768

// ---------------- K0: f32 -> bf16 conversions + bias concat ----------------
__global__ __launch_bounds__(256) void convert_kernel(
    const float* __restrict__ hs, const float* __restrict__ wq, const float* __restrict__ wk,
    const float* __restrict__ wv, const float* __restrict__ wo,
    const float* __restrict__ bq, const float* __restrict__ bk, const float* __restrict__ bv,
    u16* __restrict__ hsb, u16* __restrict__ wqkvb, u16* __restrict__ wob,
    float* __restrict__ biasqkv)
{
  int t = blockIdx.x * 256 + threadIdx.x;
  long i = (long)t * 8;
  const float* src;
  u16* dst;
  if (i < HS_N)              { src = hs + i;                  dst = hsb + i; }
  else if (i < HS_N + W_N)   { src = wq + (i - HS_N);         dst = wqkvb + (i - HS_N); }
  else if (i < HS_N + 2*W_N) { src = wk + (i - HS_N - W_N);   dst = wqkvb + (i - HS_N); }
  else if (i < HS_N + 3*W_N) { src = wv + (i - HS_N - 2*W_N); dst = wqkvb + (i - HS_N); }
  else                       { src = wo + (i - HS_N - 3*W_N); dst = wob + (i - HS_N - 3*W_N); }
  float4 a = ((const float4*)src)[0];
  float4 b = ((const float4*)src)[1];
  uint4 o;
  o.x = (u32)f2bf(a.x) | ((u32)f2bf(a.y) << 16);
  o.y = (u32)f2bf(a.z) | ((u32)f2bf(a.w) << 16);
  o.z = (u32)f2bf(b.x) | ((u32)f2bf(b.y) << 16);
  o.w = (u32)f2bf(b.z) | ((u32)f2bf(b.w) << 16);
  *(uint4*)dst = o;
  if (t < 2304) biasqkv[t] = (t < 768) ? bq[t] : ((t < 1536) ? bk[t - 768] : bv[t - 1536]);
}

// ---------------- GEMM: C = A(bf16 MxK rowmajor) @ Bt(bf16 NxK rowmajor)^T + bias -------
template<int MODE, int BM>
__global__ __launch_bounds__(256) void gemm_bt(
    const u16* __restrict__ A, const u16* __restrict__ Bt, const float* __restrict__ bias,
    float* __restrict__ outF, u16* __restrict__ Qb, u16* __restrict__ Kb, u16* __restrict__ Vtb)
{
  constexpr int LDT = 40;
  constexpr int NIT = 768 / 32;
  constexpr int MF  = BM / 32;
  constexpr int ACH = BM * 4 / 256;

  __shared__ u16 lA[BM * LDT];
  __shared__ u16 lB[128 * LDT];

  const int tid = threadIdx.x;
  const int lane = tid & 63;
  const int w = tid >> 6;
  const int l15 = lane & 15, g = lane >> 4;
  const int mBase = blockIdx.y * BM;
  const int nBase = blockIdx.x * 128;
  const int wr = w >> 1, wc = w & 1;
  const int mW = wr * (BM / 2), nW = wc * 64;

  f32x4 zero = {0.f, 0.f, 0.f, 0.f};
  f32x4 acc[MF][4];
  #pragma unroll
  for (int i = 0; i < MF; i++)
    #pragma unroll
    for (int j = 0; j < 4; j++) acc[i][j] = zero;

  uint4 ra[ACH], rb[2];
  #pragma unroll
  for (int i = 0; i < ACH; i++) {
    int c = tid + i * 256;
    ra[i] = *(const uint4*)(A + (long)(mBase + (c >> 2)) * 768 + (c & 3) * 8);
  }
  #pragma unroll
  for (int i = 0; i < 2; i++) {
    int c = tid + i * 256;
    rb[i] = *(const uint4*)(Bt + (long)(nBase + (c >> 2)) * 768 + (c & 3) * 8);
  }

  for (int kk = 0; kk < NIT; kk++) {
    __syncthreads();
    #pragma unroll
    for (int i = 0; i < ACH; i++) {
      int c = tid + i * 256;
      *(uint4*)&lA[(c >> 2) * LDT + (c & 3) * 8] = ra[i];
    }
    #pragma unroll
    for (int i = 0; i < 2; i++) {
      int c = tid + i * 256;
      *(uint4*)&lB[(c >> 2) * LDT + (c & 3) * 8] = rb[i];
    }
    __syncthreads();
    if (kk + 1 < NIT) {
      int k0 = (kk + 1) * 32;
      #pragma unroll
      for (int i = 0; i < ACH; i++) {
        int c = tid + i * 256;
        ra[i] = *(const uint4*)(A + (long)(mBase + (c >> 2)) * 768 + k0 + (c & 3) * 8);
      }
      #pragma unroll
      for (int i = 0; i < 2; i++) {
        int c = tid + i * 256;
        rb[i] = *(const uint4*)(Bt + (long)(nBase + (c >> 2)) * 768 + k0 + (c & 3) * 8);
      }
    }
    s16x8 bfr[4];
    #pragma unroll
    for (int ni = 0; ni < 4; ni++)
      bfr[ni] = *(const s16x8*)&lB[(nW + ni * 16 + l15) * LDT + g * 8];
    #pragma unroll
    for (int mi = 0; mi < MF; mi++) {
      s16x8 afr = *(const s16x8*)&lA[(mW + mi * 16 + l15) * LDT + g * 8];
      #pragma unroll
      for (int ni = 0; ni < 4; ni++)
        acc[mi][ni] = __builtin_amdgcn_mfma_f32_16x16x32_bf16(afr, bfr[ni], acc[mi][ni], 0, 0, 0);
    }
  }

  #pragma unroll
  for (int mi = 0; mi < MF; mi++) {
    #pragma unroll
    for (int ni = 0; ni < 4; ni++) {
      int n = nBase + nW + ni * 16 + l15;
      int m0 = mBase + mW + mi * 16 + g * 4;
      float b = bias[n];
      float v0 = acc[mi][ni][0] + b;
      float v1 = acc[mi][ni][1] + b;
      float v2 = acc[mi][ni][2] + b;
      float v3 = acc[mi][ni][3] + b;
      if constexpr (MODE == 1) {
        outF[(long)m0 * 768 + n] = v0;
        outF[(long)(m0 + 1) * 768 + n] = v1;
        outF[(long)(m0 + 2) * 768 + n] = v2;
        outF[(long)(m0 + 3) * 768 + n] = v3;
      } else {
        int typ = n / 768;
        int hn = n - typ * 768;
        int h = hn >> 6, d = hn & 63;
        int b_ = m0 >> 10, s0 = m0 & 1023;
        long bh = b_ * 12 + h;
        if (typ == 2) {
          u64 pk = (u64)((u32)f2bf(v0) | ((u32)f2bf(v1) << 16)) |
                   (((u64)((u32)f2bf(v2) | ((u32)f2bf(v3) << 16))) << 32);
          *(u64*)(Vtb + (bh << 16) + (d << 10) + s0) = pk;
        } else {
          u16* dst = (typ == 0 ? Qb : Kb) + (bh << 16) + ((long)s0 << 6) + d;
          dst[0]   = f2bf(v0);
          dst[64]  = f2bf(v1);
          dst[128] = f2bf(v2);
          dst[192] = f2bf(v3);
        }
      }
    }
  }
}

// ---------------- K2: build qAe/kAe extended features + beta ----------------
__global__ __launch_bounds__(256) void qk_ext_kernel(
    const u16* __restrict__ Qb, const u16* __restrict__ Kb, const float* __restrict__ Am,
    const float* __restrict__ mask, u16* __restrict__ qAe, u16* __restrict__ kAe,
    float* __restrict__ beta2)
{
  const bool isK = blockIdx.x >= 192;
  const int rb = blockIdx.x * 256 - (isK ? 49152 : 0);
  const int h = (rb >> 10) % 12;
  const int row = rb + threadIdx.x;
  const int bh = row >> 10;
  const int s = row & 1023;
  const int b_ = bh / 12;

  const u16* src = (isK ? Kb : Qb) + ((long)row << 6);
  union { uint4 v4[8]; u32 u[32]; } c;
  #pragma unroll
  for (int i = 0; i < 8; i++) c.v4[i] = ((const uint4*)src)[i];

  const float* Ah = Am + h * 1024;
  float acc[16];
  #pragma unroll
  for (int r = 0; r < 16; r++) acc[r] = 0.f;
  float s2 = 0.f;
  #pragma unroll
  for (int d = 0; d < 64; d++) {
    u32 wd = c.u[d >> 1];
    float qd = bf2f((u16)((d & 1) ? (wd >> 16) : (wd & 0xffffu)));
    s2 += qd * qd;
    #pragma unroll
    for (int r = 0; r < 16; r++) acc[r] += qd * Ah[d * 16 + r];
  }

  union { u16 us[128]; uint4 v4[16]; } o;
  const float sA = isK ? 1.0f : 0.25f;
  const float sQ = isK ? 1e-3f : 0.25e-3f;
  #pragma unroll
  for (int r = 0; r < 16; r++) o.us[r] = f2bf(acc[r] * sA);
  #pragma unroll
  for (int d = 0; d < 64; d++) {
    u32 wd = c.u[d >> 1];
    float qd = bf2f((u16)((d & 1) ? (wd >> 16) : (wd & 0xffffu)));
    o.us[16 + d] = f2bf(qd * sQ);
  }
  #pragma unroll
  for (int j = 80; j < 128; j++) o.us[j] = 0;

  u16* dst = (isK ? kAe : qAe) + ((long)row << 7);
  #pragma unroll
  for (int i = 0; i < 16; i++) ((uint4*)dst)[i] = o.v4[i];

  if (isK) {
    float kk = 1e-6f * s2;
    #pragma unroll
    for (int r = 0; r < 16; r++) kk += acc[r] * acc[r];
    beta2[row] = -0.125f * kk + mask[(b_ << 10) + s];
  }
}

// ---------------- K3: attention v3 — async-pipelined (T3/T4 2-phase) ----------------
// grid 768 = 48 bh x 16 qtiles(64 rows), XCD-swizzled; block 128 = 2 waves.
// Wave owns 32 q rows end-to-end (no cross-wave reduce). Full t-loop, chunks of 32.
// K chunk staged in LDS via global_load_lds (dbuf, XOR-swizzled both-sides);
// V/beta reg-prefetched 1 chunk ahead via asm loads; counted vmcnt(6)/vmcnt(10).
__global__ __launch_bounds__(128, 2) void attn_kernel(
    const u16* __restrict__ qAe, const u16* __restrict__ kAe, const u16* __restrict__ Vtb,
    const float* __restrict__ beta2, u16* __restrict__ ctxb)
{
  const int tid = threadIdx.x;
  const int lane = tid & 63;
  const int w = tid >> 6;
  const int l15 = lane & 15, g = lane >> 4;
  const int wid = (blockIdx.x & 7) * 96 + (blockIdx.x >> 3);  // 768 = 8*96, bijective
  const int bh = wid >> 4;
  const int qt = wid & 15;
  const int q0 = qt * 64 + w * 32;

  __shared__ __align__(16) char sm[2 * 8192 + 2 * 2560];
  char* kb0 = sm;                       // K buf0: 32 rows x 256B, swizzled
  char* kb1 = sm + 8192;                // K buf1
  char* Pw  = sm + 16384 + w * 2560;    // per-wave P: 32 rows x 80B

  const u16* qbase = qAe + ((long)(bh * 1024 + q0) << 7);
  const u16* kbase = kAe + ((long)bh << 17);
  const u16* vbase = Vtb + ((long)bh << 16);
  const float* betab = beta2 + (bh << 10);

  // --- asm-load qAe B-fragments (ks=0..2; cols 96..127 are zero-pad) : 6 VMEM
  u32x4 bqv[2][3];
  #pragma unroll
  for (int qf = 0; qf < 2; qf++)
    #pragma unroll
    for (int ks = 0; ks < 3; ks++) {
      const u16* a = qbase + ((qf * 16 + l15) << 7) + ks * 32 + g * 8;
      asm volatile("global_load_dwordx4 %0, %1, off" : "=v"(bqv[qf][ks]) : "v"(a));
    }

  // stage K chunk c into buf: wave w covers instrs i = w*4..w*4+3 (rows 16w..16w+15)
  auto stageK = [&](int c, char* buf) {
    const int t0 = c * 32;
    #pragma unroll
    for (int i2 = 0; i2 < 4; i2++) {
      int i = w * 4 + i2;
      int r = i * 4 + (lane >> 4);
      int col = ((lane & 15) ^ (r & 7)) * 8;          // pre-swizzled source (rule #21)
      const u16* gsrc = kbase + (long)(t0 + r) * 128 + col;
      gl2lds16(gsrc, buf + i * 1024);
    }
  };
  // V fragment prefetch (4 VMEM) and beta prefetch (2 VMEM)
  auto loadV = [&](int c, u32x4 (&dst)[4]) {
    const int t0 = c * 32;
    #pragma unroll
    for (int df = 0; df < 4; df++) {
      const u16* a = vbase + ((df * 16 + l15) << 10) + t0 + g * 8;
      asm volatile("global_load_dwordx4 %0, %1, off" : "=v"(dst[df]) : "v"(a));
    }
  };
  auto loadB = [&](int c, u32x4 (&dst)[2]) {
    #pragma unroll
    for (int tf = 0; tf < 2; tf++) {
      const float* a = betab + c * 32 + tf * 16 + g * 4;
      asm volatile("global_load_dwordx4 %0, %1, off" : "=v"(dst[tf]) : "v"(a));
    }
  };

  f32x4 zero = {0.f, 0.f, 0.f, 0.f};
  f32x4 cacc[2][4];
  #pragma unroll
  for (int a = 0; a < 2; a++)
    #pragma unroll
    for (int b = 0; b < 4; b++) cacc[a][b] = zero;
  float rsum[2] = {0.f, 0.f};

  u32x4 vA[4], vB[4], bA[2], bB[2];

  // VMEM FIFO per iter (steady): [K(c)x4][V(c)x4][B(c)x2] then issue K(c+1),V(c+1),B(c+1).
  // vmcnt(6): K(c) landed (6 = V(c)+B(c) may remain). vmcnt(10): V(c),B(c) landed.
  auto chunk = [&](auto LASTC, int c, char* bufc, char* bufn,
                   u32x4 (&curV)[4], u32x4 (&curB)[2],
                   u32x4 (&nxtV)[4], u32x4 (&nxtB)[2]) {
    constexpr bool LAST = decltype(LASTC)::value;
    asm volatile("s_waitcnt vmcnt(6)" ::: "memory");
    asm volatile("s_barrier" ::: "memory");
    if constexpr (!LAST) {
      stageK(c + 1, bufn);
      loadV(c + 1, nxtV);
      loadB(c + 1, nxtB);
    }
    // phase A: S^T = K @ Q^T on staged chunk
    f32x4 sacc[2][2];
    sacc[0][0] = zero; sacc[0][1] = zero; sacc[1][0] = zero; sacc[1][1] = zero;
    #pragma unroll
    for (int tf = 0; tf < 2; tf++)
      #pragma unroll
      for (int ks = 0; ks < 3; ks++) {
        s16x8 ak = *(const s16x8*)(bufc + (tf * 16 + l15) * 256 +
                                   ((ks * 64 + g * 16) ^ ((l15 & 7) << 4)));
        s16x8 b0 = __builtin_bit_cast(s16x8, bqv[0][ks]);
        s16x8 b1 = __builtin_bit_cast(s16x8, bqv[1][ks]);
        sacc[tf][0] = __builtin_amdgcn_mfma_f32_16x16x32_bf16(ak, b0, sacc[tf][0], 0, 0, 0);
        sacc[tf][1] = __builtin_amdgcn_mfma_f32_16x16x32_bf16(ak, b1, sacc[tf][1], 0, 0, 0);
      }
    if constexpr (!LAST) asm volatile("s_waitcnt vmcnt(10)" ::: "memory");
    else                 asm volatile("s_waitcnt vmcnt(0)" ::: "memory");
    __builtin_amdgcn_sched_barrier(0);
    // exp + P write (swizzled rows, stride 80B)
    #pragma unroll
    for (int tf = 0; tf < 2; tf++) {
      f32x4 bb = __builtin_bit_cast(f32x4, curB[tf]);
      #pragma unroll
      for (int qf = 0; qf < 2; qf++) {
        float e0 = __expf(sacc[tf][qf][0] + bb[0]);
        float e1 = __expf(sacc[tf][qf][1] + bb[1]);
        float e2 = __expf(sacc[tf][qf][2] + bb[2]);
        float e3 = __expf(sacc[tf][qf][3] + bb[3]);
        rsum[qf] += e0 + e1 + e2 + e3;
        u32 lo = (u32)f2bf(e0) | ((u32)f2bf(e1) << 16);
        u32 hi = (u32)f2bf(e2) | ((u32)f2bf(e3) << 16);
        *(u64*)(Pw + (qf * 16 + l15) * 80 + tf * 32 + g * 8) =
            (u64)lo | ((u64)hi << 32);
      }
    }
    // phase B: ctx += P @ V (V frags from regs, prefetched last iter)
    #pragma unroll
    for (int qf = 0; qf < 2; qf++) {
      s16x8 ap = *(const s16x8*)(Pw + (qf * 16 + l15) * 80 + g * 16);
      #pragma unroll
      for (int df = 0; df < 4; df++) {
        s16x8 bv = __builtin_bit_cast(s16x8, curV[df]);
        cacc[qf][df] = __builtin_amdgcn_mfma_f32_16x16x32_bf16(ap, bv, cacc[qf][df], 0, 0, 0);
      }
    }
  };

  // prologue: queue = [bq x6][K0 x4][V0 x4][B0 x2]
  stageK(0, kb0);
  loadV(0, vA);
  loadB(0, bA);

  std::integral_constant<bool, false> F;
  std::integral_constant<bool, true>  T;
  #pragma unroll 1
  for (int c2 = 0; c2 < 15; c2++) {
    chunk(F, 2 * c2,     kb0, kb1, vA, bA, vB, bB);
    chunk(F, 2 * c2 + 1, kb1, kb0, vB, bB, vA, bA);
  }
  chunk(F, 30, kb0, kb1, vA, bA, vB, bB);
  chunk(T, 31, kb1, kb0, vB, bB, vA, bA);

  // epilogue: per-wave softmax normalize + write (no cross-wave reduce)
  #pragma unroll
  for (int qf = 0; qf < 2; qf++) {
    rsum[qf] += __shfl_xor(rsum[qf], 16);
    rsum[qf] += __shfl_xor(rsum[qf], 32);
  }
  const int b_ = bh / 12, h = bh % 12;
  #pragma unroll
  for (int qf = 0; qf < 2; qf++) {
    #pragma unroll
    for (int j = 0; j < 4; j++) {
      float rs = __shfl(rsum[qf], g * 4 + j);
      float rinv = 1.0f / rs;
      int qg = q0 + qf * 16 + g * 4 + j;
      long base = ((long)(b_ * 1024 + qg)) * 768 + h * 64;
      #pragma unroll
      for (int df = 0; df < 4; df++)
        ctxb[base + df * 16 + l15] = f2bf(cacc[qf][df][j] * rinv);
    }
  }
}

// ---------------- launcher ----------------
extern "C" void kernel_launch(void* const* d_in, const int* in_sizes, int n_in,
                              void* d_out, int out_size, void* d_ws, size_t ws_size,
                              hipStream_t stream)
{
  (void)in_sizes; (void)n_in; (void)out_size; (void)ws_size;
  const float* hs   = (const float*)d_in[0];
  const float* mask = (const float*)d_in[1];
  const float* Wq   = (const float*)d_in[2];
  const float* bq   = (const float*)d_in[3];
  const float* Wk   = (const float*)d_in[4];
  const float* bk   = (const float*)d_in[5];
  const float* Wv   = (const float*)d_in[6];
  const float* bv   = (const float*)d_in[7];
  const float* Wo   = (const float*)d_in[8];
  const float* bo   = (const float*)d_in[9];
  const float* Am   = (const float*)d_in[10];
  float* out = (float*)d_out;

  char* p = (char*)d_ws;
  u16* hsb      = (u16*)p;   p += 6291456;
  u16* wqkvb    = (u16*)p;   p += 3538944;
  u16* wob      = (u16*)p;   p += 1179648;
  float* biasqkv= (float*)p; p += 9216;
  u16* Qb       = (u16*)p;   p += 6291456;
  u16* Kb       = (u16*)p;   p += 6291456;
  u16* Vtb      = (u16*)p;   p += 6291456;
  u16* qAeb     = (u16*)p;   p += 12582912;
  u16* kAeb     = (u16*)p;   p += 12582912;
  float* beta2  = (float*)p; p += 196608;
  u16* ctxb     = (u16*)p;   p += 6291456;

  convert_kernel<<<2688, 256, 0, stream>>>(hs, Wq, Wk, Wv, Wo, bq, bk, bv,
                                           hsb, wqkvb, wob, biasqkv);
  gemm_bt<0, 128><<<dim3(18, 32), 256, 0, stream>>>(hsb, wqkvb, biasqkv,
                                                    nullptr, Qb, Kb, Vtb);
  qk_ext_kernel<<<384, 256, 0, stream>>>(Qb, Kb, Am, mask, qAeb, kAeb, beta2);
  attn_kernel<<<768, 128, 0, stream>>>(qAeb, kAeb, Vtb, beta2, ctxb);
  gemm_bt<1, 64><<<dim3(6, 64), 256, 0, stream>>>(ctxb, wob, bo, out,
                                                  nullptr, nullptr, nullptr);
}

// Round 4
// 98.415 us; speedup vs baseline: 2.5921x; 1.8939x over previous
//
#include <hip/hip_runtime.h>

typedef __attribute__((ext_vector_type(8))) short s16x8;
typedef __attribute__((ext_vector_type(4))) float f32x4;
typedef __attribute__((ext_vector_type(4))) unsigned int u32x4;
typedef unsigned short u16;
typedef unsigned int u32;
typedef unsigned long long u64;

__device__ __forceinline__ u16 f2bf(float f) {
  u32 u = __float_as_uint(f);
  u32 r = u + 0x7fffu + ((u >> 16) & 1u);
  return (u16)(r >> 16);
}
__device__ __forceinline__ float bf2f(u16 h) {
  return __uint_as_float(((u32)h) << 16);
}

typedef __attribute__((address_space(3))) char lds_char_t;
typedef __attribute__((address_space(1))) const char glb_char_t;
__device__ __forceinline__ void gl2lds16(const void* g, void* l) {
  __builtin_amdgcn_global_load_lds((glb_char_t*)g, (lds_char_t*)l, 16, 0, 0);
}

#define HS_N 3145728   // 4096*768
#define W_N  589824    // 768*768

// ---------------- K0: f32 -> bf16 conversions + bias concat ----------------
__global__ __launch_bounds__(256) void convert_kernel(
    const float* __restrict__ hs, const float* __restrict__ wq, const float* __restrict__ wk,
    const float* __restrict__ wv, const float* __restrict__ wo,
    const float* __restrict__ bq, const float* __restrict__ bk, const float* __restrict__ bv,
    u16* __restrict__ hsb, u16* __restrict__ wqkvb, u16* __restrict__ wob,
    float* __restrict__ biasqkv)
{
  int t = blockIdx.x * 256 + threadIdx.x;
  long i = (long)t * 8;
  const float* src;
  u16* dst;
  if (i < HS_N)              { src = hs + i;                  dst = hsb + i; }
  else if (i < HS_N + W_N)   { src = wq + (i - HS_N);         dst = wqkvb + (i - HS_N); }
  else if (i < HS_N + 2*W_N) { src = wk + (i - HS_N - W_N);   dst = wqkvb + (i - HS_N); }
  else if (i < HS_N + 3*W_N) { src = wv + (i - HS_N - 2*W_N); dst = wqkvb + (i - HS_N); }
  else                       { src = wo + (i - HS_N - 3*W_N); dst = wob + (i - HS_N - 3*W_N); }
  float4 a = ((const float4*)src)[0];
  float4 b = ((const float4*)src)[1];
  uint4 o;
  o.x = (u32)f2bf(a.x) | ((u32)f2bf(a.y) << 16);
  o.y = (u32)f2bf(a.z) | ((u32)f2bf(a.w) << 16);
  o.z = (u32)f2bf(b.x) | ((u32)f2bf(b.y) << 16);
  o.w = (u32)f2bf(b.z) | ((u32)f2bf(b.w) << 16);
  *(uint4*)dst = o;
  if (t < 2304) biasqkv[t] = (t < 768) ? bq[t] : ((t < 1536) ? bk[t - 768] : bv[t - 1536]);
}

// ---------------- GEMM v2: async-pipelined, C = A @ Bt^T + bias ----------------
// BM=64, BN=128, BK=64, 4 waves (2x2), tri-buffered LDS via global_load_lds,
// 1 s_barrier/iter, counted vmcnt(6). LDS rows 128B, XOR-swizzle (row&7)<<4 both-sides.
// MODE 0: QKV proj -> Q[bh][s][d], K[bh][s][d], V^T[bh][d][s] (V via LDS transpose)
// MODE 1: f32 output [M][768]
template<int MODE>
__global__ __launch_bounds__(256, 2) void gemm_bt(
    const u16* __restrict__ A, const u16* __restrict__ Bt, const float* __restrict__ bias,
    float* __restrict__ outF, u16* __restrict__ Qb, u16* __restrict__ Kb, u16* __restrict__ Vtb)
{
  constexpr int NT = (MODE == 0) ? 18 : 6;      // n-tiles
  constexpr int CPX = NT * 64 / 8;              // blocks per XCD chunk

  __shared__ __align__(16) char sm[73728];      // 3x8K (A) + 3x16K (B)
  char* const smA = sm;
  char* const smB = sm + 24576;

  const int tid = threadIdx.x;
  const int lane = tid & 63;
  const int w = tid >> 6;
  const int l15 = lane & 15, g = lane >> 4;
  const int wid = (blockIdx.x & 7) * CPX + (blockIdx.x >> 3);   // bijective XCD swizzle
  const int bx = wid % NT, by = wid / NT;
  const int mBase = by * 64;
  const int nBase = bx * 128;
  const int wr = w >> 1, wc = w & 1;
  const int mW = wr * 32, nW = wc * 64;

  f32x4 zero = {0.f, 0.f, 0.f, 0.f};
  f32x4 acc[2][4];
  #pragma unroll
  for (int i = 0; i < 2; i++)
    #pragma unroll
    for (int j = 0; j < 4; j++) acc[i][j] = zero;

  const u16* Arow = A + (long)mBase * 768;
  const u16* Brow = Bt + (long)nBase * 768;

  // stage tile c into buffer kb: 2 A-insts + 4 B-insts per thread (16B each).
  // LDS dest is wave-uniform base + lane*16 (HW rule); source pre-swizzled.
  auto stage = [&](int c, int kb) {
    const int k0 = c * 64;
    #pragma unroll
    for (int i = 0; i < 2; i++) {
      int o = (i * 256 + tid) * 16;             // linear LDS offset this lane fills
      int r = o >> 7;                           // A row 0..63
      int sl = ((o >> 4) & 7) ^ (r & 7);        // inverse-swizzled source slot
      gl2lds16(Arow + (long)r * 768 + k0 + sl * 8,
               smA + kb * 8192 + i * 4096 + w * 1024);
    }
    #pragma unroll
    for (int i = 0; i < 4; i++) {
      int o = (i * 256 + tid) * 16;
      int r = o >> 7;                           // B row 0..127
      int sl = ((o >> 4) & 7) ^ (r & 7);
      gl2lds16(Brow + (long)r * 768 + k0 + sl * 8,
               smB + kb * 16384 + i * 4096 + w * 1024);
    }
  };

  auto compute = [&](int kb) {
    const char* bufA = smA + kb * 8192;
    const char* bufB = smB + kb * 16384;
    #pragma unroll
    for (int kh = 0; kh < 2; kh++) {
      s16x8 af[2], bf[4];
      #pragma unroll
      for (int mi = 0; mi < 2; mi++) {
        int R = mW + mi * 16 + l15;
        af[mi] = *(const s16x8*)(bufA + R * 128 + (((kh * 4 + g) ^ (l15 & 7)) << 4));
      }
      #pragma unroll
      for (int ni = 0; ni < 4; ni++) {
        int R = nW + ni * 16 + l15;
        bf[ni] = *(const s16x8*)(bufB + R * 128 + (((kh * 4 + g) ^ (l15 & 7)) << 4));
      }
      #pragma unroll
      for (int mi = 0; mi < 2; mi++)
        #pragma unroll
        for (int ni = 0; ni < 4; ni++)
          acc[mi][ni] = __builtin_amdgcn_mfma_f32_16x16x32_bf16(af[mi], bf[ni], acc[mi][ni], 0, 0, 0);
    }
  };

  // body(c): issue stage(c+1), wait tile c (vmcnt(6): c+1's 6 stay in flight),
  // barrier (all waves' tile-c loads landed), compute on buffer c%3.
  auto body = [&](int c, int kb, int kbn) {
    if (c < 11) { stage(c + 1, kbn); asm volatile("s_waitcnt vmcnt(6)" ::: "memory"); }
    else        { asm volatile("s_waitcnt vmcnt(0)" ::: "memory"); }
    asm volatile("s_barrier" ::: "memory");
    compute(kb);
  };

  stage(0, 0);
  #pragma unroll 1
  for (int cc = 0; cc < 4; cc++) {
    body(cc * 3,     0, 1);
    body(cc * 3 + 1, 1, 2);
    body(cc * 3 + 2, 2, 0);
  }
  __syncthreads();   // all LDS reads done; safe to reuse sm in epilogue

  const int b_ = mBase >> 10;
  const int s0b = mBase & 1023;

  if constexpr (MODE == 1) {
    #pragma unroll
    for (int mi = 0; mi < 2; mi++)
      #pragma unroll
      for (int ni = 0; ni < 4; ni++) {
        int n = nBase + nW + ni * 16 + l15;
        int m0 = mBase + mW + mi * 16 + g * 4;
        float bb = bias[n];
        outF[(long)m0 * 768 + n]       = acc[mi][ni][0] + bb;
        outF[(long)(m0 + 1) * 768 + n] = acc[mi][ni][1] + bb;
        outF[(long)(m0 + 2) * 768 + n] = acc[mi][ni][2] + bb;
        outF[(long)(m0 + 3) * 768 + n] = acc[mi][ni][3] + bb;
      }
  } else {
    const int typ = bx / 6;                     // 0=Q, 1=K, 2=V (tile-uniform)
    if (typ < 2) {
      u16* qk = (typ == 0) ? Qb : Kb;
      #pragma unroll
      for (int mi = 0; mi < 2; mi++)
        #pragma unroll
        for (int ni = 0; ni < 4; ni++) {
          int n = nBase + nW + ni * 16 + l15;
          int hn = n - typ * 768;
          int h = hn >> 6, d = hn & 63;
          long bh = (long)b_ * 12 + h;
          int s0 = s0b + mW + mi * 16 + g * 4;
          float bb = bias[n];
          u16* dst = qk + (bh << 16) + ((long)s0 << 6) + d;
          dst[0]   = f2bf(acc[mi][ni][0] + bb);
          dst[64]  = f2bf(acc[mi][ni][1] + bb);
          dst[128] = f2bf(acc[mi][ni][2] + bb);
          dst[192] = f2bf(acc[mi][ni][3] + bb);
        }
    } else {
      // V: stage C^T (bf16, rows=n 0..127 of 72 u16 = 144B, padded) then
      // write V^T[bh][d][s] in 64B-contiguous runs.
      u16* ct = (u16*)sm;
      #pragma unroll
      for (int mi = 0; mi < 2; mi++)
        #pragma unroll
        for (int ni = 0; ni < 4; ni++) {
          int nr = nW + ni * 16 + l15;
          int mr = mW + mi * 16 + g * 4;
          float bb = bias[nBase + nr];
          u32 lo = (u32)f2bf(acc[mi][ni][0] + bb) | ((u32)f2bf(acc[mi][ni][1] + bb) << 16);
          u32 hi = (u32)f2bf(acc[mi][ni][2] + bb) | ((u32)f2bf(acc[mi][ni][3] + bb) << 16);
          *(u64*)(ct + nr * 72 + mr) = (u64)lo | ((u64)hi << 32);
        }
      __syncthreads();
      int dr = tid >> 1, part = tid & 1;
      int hn = (bx - 12) * 128 + dr;
      int h = hn >> 6, d = hn & 63;
      long bh = (long)b_ * 12 + h;
      u16* dst = Vtb + (bh << 16) + (d << 10) + s0b + part * 32;
      const u16* srl = ct + dr * 72 + part * 32;
      #pragma unroll
      for (int i = 0; i < 4; i++)
        *(uint4*)(dst + i * 8) = *(const uint4*)(srl + i * 8);
    }
  }
}

// ---------------- K2: build qAe/kAe extended features + beta ----------------
__global__ __launch_bounds__(256) void qk_ext_kernel(
    const u16* __restrict__ Qb, const u16* __restrict__ Kb, const float* __restrict__ Am,
    const float* __restrict__ mask, u16* __restrict__ qAe, u16* __restrict__ kAe,
    float* __restrict__ beta2)
{
  const bool isK = blockIdx.x >= 192;
  const int rb = blockIdx.x * 256 - (isK ? 49152 : 0);
  const int h = (rb >> 10) % 12;
  const int row = rb + threadIdx.x;
  const int bh = row >> 10;
  const int s = row & 1023;
  const int b_ = bh / 12;

  const u16* src = (isK ? Kb : Qb) + ((long)row << 6);
  union { uint4 v4[8]; u32 u[32]; } c;
  #pragma unroll
  for (int i = 0; i < 8; i++) c.v4[i] = ((const uint4*)src)[i];

  const float* Ah = Am + h * 1024;
  float acc[16];
  #pragma unroll
  for (int r = 0; r < 16; r++) acc[r] = 0.f;
  float s2 = 0.f;
  #pragma unroll
  for (int d = 0; d < 64; d++) {
    u32 wd = c.u[d >> 1];
    float qd = bf2f((u16)((d & 1) ? (wd >> 16) : (wd & 0xffffu)));
    s2 += qd * qd;
    #pragma unroll
    for (int r = 0; r < 16; r++) acc[r] += qd * Ah[d * 16 + r];
  }

  union { u16 us[128]; uint4 v4[16]; } o;
  const float sA = isK ? 1.0f : 0.25f;
  const float sQ = isK ? 1e-3f : 0.25e-3f;
  #pragma unroll
  for (int r = 0; r < 16; r++) o.us[r] = f2bf(acc[r] * sA);
  #pragma unroll
  for (int d = 0; d < 64; d++) {
    u32 wd = c.u[d >> 1];
    float qd = bf2f((u16)((d & 1) ? (wd >> 16) : (wd & 0xffffu)));
    o.us[16 + d] = f2bf(qd * sQ);
  }
  #pragma unroll
  for (int j = 80; j < 128; j++) o.us[j] = 0;

  u16* dst = (isK ? kAe : qAe) + ((long)row << 7);
  #pragma unroll
  for (int i = 0; i < 16; i++) ((uint4*)dst)[i] = o.v4[i];

  if (isK) {
    float kk = 1e-6f * s2;
    #pragma unroll
    for (int r = 0; r < 16; r++) kk += acc[r] * acc[r];
    beta2[row] = -0.125f * kk + mask[(b_ << 10) + s];
  }
}

// ---------------- K3: attention — async-pipelined (unchanged from R3) ----------------
__global__ __launch_bounds__(128, 2) void attn_kernel(
    const u16* __restrict__ qAe, const u16* __restrict__ kAe, const u16* __restrict__ Vtb,
    const float* __restrict__ beta2, u16* __restrict__ ctxb)
{
  const int tid = threadIdx.x;
  const int lane = tid & 63;
  const int w = tid >> 6;
  const int l15 = lane & 15, g = lane >> 4;
  const int wid = (blockIdx.x & 7) * 96 + (blockIdx.x >> 3);  // 768 = 8*96, bijective
  const int bh = wid >> 4;
  const int qt = wid & 15;
  const int q0 = qt * 64 + w * 32;

  __shared__ __align__(16) char sm[2 * 8192 + 2 * 2560];
  char* kb0 = sm;
  char* kb1 = sm + 8192;
  char* Pw  = sm + 16384 + w * 2560;

  const u16* qbase = qAe + ((long)(bh * 1024 + q0) << 7);
  const u16* kbase = kAe + ((long)bh << 17);
  const u16* vbase = Vtb + ((long)bh << 16);
  const float* betab = beta2 + (bh << 10);

  u32x4 bqv[2][3];
  #pragma unroll
  for (int qf = 0; qf < 2; qf++)
    #pragma unroll
    for (int ks = 0; ks < 3; ks++) {
      const u16* a = qbase + ((qf * 16 + l15) << 7) + ks * 32 + g * 8;
      asm volatile("global_load_dwordx4 %0, %1, off" : "=v"(bqv[qf][ks]) : "v"(a));
    }

  auto stageK = [&](int c, char* buf) {
    const int t0 = c * 32;
    #pragma unroll
    for (int i2 = 0; i2 < 4; i2++) {
      int i = w * 4 + i2;
      int r = i * 4 + (lane >> 4);
      int col = ((lane & 15) ^ (r & 7)) * 8;
      const u16* gsrc = kbase + (long)(t0 + r) * 128 + col;
      gl2lds16(gsrc, buf + i * 1024);
    }
  };
  auto loadV = [&](int c, u32x4 (&dst)[4]) {
    const int t0 = c * 32;
    #pragma unroll
    for (int df = 0; df < 4; df++) {
      const u16* a = vbase + ((df * 16 + l15) << 10) + t0 + g * 8;
      asm volatile("global_load_dwordx4 %0, %1, off" : "=v"(dst[df]) : "v"(a));
    }
  };
  auto loadB = [&](int c, u32x4 (&dst)[2]) {
    #pragma unroll
    for (int tf = 0; tf < 2; tf++) {
      const float* a = betab + c * 32 + tf * 16 + g * 4;
      asm volatile("global_load_dwordx4 %0, %1, off" : "=v"(dst[tf]) : "v"(a));
    }
  };

  f32x4 zero = {0.f, 0.f, 0.f, 0.f};
  f32x4 cacc[2][4];
  #pragma unroll
  for (int a = 0; a < 2; a++)
    #pragma unroll
    for (int b = 0; b < 4; b++) cacc[a][b] = zero;
  float rsum[2] = {0.f, 0.f};

  u32x4 vA[4], vB[4], bA[2], bB[2];

  auto chunk = [&](auto LASTC, int c, char* bufc, char* bufn,
                   u32x4 (&curV)[4], u32x4 (&curB)[2],
                   u32x4 (&nxtV)[4], u32x4 (&nxtB)[2]) {
    constexpr bool LAST = decltype(LASTC)::value;
    asm volatile("s_waitcnt vmcnt(6)" ::: "memory");
    asm volatile("s_barrier" ::: "memory");
    if constexpr (!LAST) {
      stageK(c + 1, bufn);
      loadV(c + 1, nxtV);
      loadB(c + 1, nxtB);
    }
    f32x4 sacc[2][2];
    sacc[0][0] = zero; sacc[0][1] = zero; sacc[1][0] = zero; sacc[1][1] = zero;
    #pragma unroll
    for (int tf = 0; tf < 2; tf++)
      #pragma unroll
      for (int ks = 0; ks < 3; ks++) {
        s16x8 ak = *(const s16x8*)(bufc + (tf * 16 + l15) * 256 +
                                   ((ks * 64 + g * 16) ^ ((l15 & 7) << 4)));
        s16x8 b0 = __builtin_bit_cast(s16x8, bqv[0][ks]);
        s16x8 b1 = __builtin_bit_cast(s16x8, bqv[1][ks]);
        sacc[tf][0] = __builtin_amdgcn_mfma_f32_16x16x32_bf16(ak, b0, sacc[tf][0], 0, 0, 0);
        sacc[tf][1] = __builtin_amdgcn_mfma_f32_16x16x32_bf16(ak, b1, sacc[tf][1], 0, 0, 0);
      }
    if constexpr (!LAST) asm volatile("s_waitcnt vmcnt(10)" ::: "memory");
    else                 asm volatile("s_waitcnt vmcnt(0)" ::: "memory");
    __builtin_amdgcn_sched_barrier(0);
    #pragma unroll
    for (int tf = 0; tf < 2; tf++) {
      f32x4 bb = __builtin_bit_cast(f32x4, curB[tf]);
      #pragma unroll
      for (int qf = 0; qf < 2; qf++) {
        float e0 = __expf(sacc[tf][qf][0] + bb[0]);
        float e1 = __expf(sacc[tf][qf][1] + bb[1]);
        float e2 = __expf(sacc[tf][qf][2] + bb[2]);
        float e3 = __expf(sacc[tf][qf][3] + bb[3]);
        rsum[qf] += e0 + e1 + e2 + e3;
        u32 lo = (u32)f2bf(e0) | ((u32)f2bf(e1) << 16);
        u32 hi = (u32)f2bf(e2) | ((u32)f2bf(e3) << 16);
        *(u64*)(Pw + (qf * 16 + l15) * 80 + tf * 32 + g * 8) =
            (u64)lo | ((u64)hi << 32);
      }
    }
    #pragma unroll
    for (int qf = 0; qf < 2; qf++) {
      s16x8 ap = *(const s16x8*)(Pw + (qf * 16 + l15) * 80 + g * 16);
      #pragma unroll
      for (int df = 0; df < 4; df++) {
        s16x8 bv = __builtin_bit_cast(s16x8, curV[df]);
        cacc[qf][df] = __builtin_amdgcn_mfma_f32_16x16x32_bf16(ap, bv, cacc[qf][df], 0, 0, 0);
      }
    }
  };

  stageK(0, kb0);
  loadV(0, vA);
  loadB(0, bA);

  std::integral_constant<bool, false> F;
  std::integral_constant<bool, true>  T;
  #pragma unroll 1
  for (int c2 = 0; c2 < 15; c2++) {
    chunk(F, 2 * c2,     kb0, kb1, vA, bA, vB, bB);
    chunk(F, 2 * c2 + 1, kb1, kb0, vB, bB, vA, bA);
  }
  chunk(F, 30, kb0, kb1, vA, bA, vB, bB);
  chunk(T, 31, kb1, kb0, vB, bB, vA, bA);

  #pragma unroll
  for (int qf = 0; qf < 2; qf++) {
    rsum[qf] += __shfl_xor(rsum[qf], 16);
    rsum[qf] += __shfl_xor(rsum[qf], 32);
  }
  const int b_ = bh / 12, h = bh % 12;
  #pragma unroll
  for (int qf = 0; qf < 2; qf++) {
    #pragma unroll
    for (int j = 0; j < 4; j++) {
      float rs = __shfl(rsum[qf], g * 4 + j);
      float rinv = 1.0f / rs;
      int qg = q0 + qf * 16 + g * 4 + j;
      long base = ((long)(b_ * 1024 + qg)) * 768 + h * 64;
      #pragma unroll
      for (int df = 0; df < 4; df++)
        ctxb[base + df * 16 + l15] = f2bf(cacc[qf][df][j] * rinv);
    }
  }
}

// ---------------- launcher ----------------
extern "C" void kernel_launch(void* const* d_in, const int* in_sizes, int n_in,
                              void* d_out, int out_size, void* d_ws, size_t ws_size,
                              hipStream_t stream)
{
  (void)in_sizes; (void)n_in; (void)out_size; (void)ws_size;
  const float* hs   = (const float*)d_in[0];
  const float* mask = (const float*)d_in[1];
  const float* Wq   = (const float*)d_in[2];
  const float* bq   = (const float*)d_in[3];
  const float* Wk   = (const float*)d_in[4];
  const float* bk   = (const float*)d_in[5];
  const float* Wv   = (const float*)d_in[6];
  const float* bv   = (const float*)d_in[7];
  const float* Wo   = (const float*)d_in[8];
  const float* bo   = (const float*)d_in[9];
  const float* Am   = (const float*)d_in[10];
  float* out = (float*)d_out;

  char* p = (char*)d_ws;
  u16* hsb      = (u16*)p;   p += 6291456;
  u16* wqkvb    = (u16*)p;   p += 3538944;
  u16* wob      = (u16*)p;   p += 1179648;
  float* biasqkv= (float*)p; p += 9216;
  u16* Qb       = (u16*)p;   p += 6291456;
  u16* Kb       = (u16*)p;   p += 6291456;
  u16* Vtb      = (u16*)p;   p += 6291456;
  u16* qAeb     = (u16*)p;   p += 12582912;
  u16* kAeb     = (u16*)p;   p += 12582912;
  float* beta2  = (float*)p; p += 196608;
  u16* ctxb     = (u16*)p;   p += 6291456;

  convert_kernel<<<2688, 256, 0, stream>>>(hs, Wq, Wk, Wv, Wo, bq, bk, bv,
                                           hsb, wqkvb, wob, biasqkv);
  gemm_bt<0><<<1152, 256, 0, stream>>>(hsb, wqkvb, biasqkv,
                                       nullptr, Qb, Kb, Vtb);
  qk_ext_kernel<<<384, 256, 0, stream>>>(Qb, Kb, Am, mask, qAeb, kAeb, beta2);
  attn_kernel<<<768, 128, 0, stream>>>(qAeb, kAeb, Vtb, beta2, ctxb);
  gemm_bt<1><<<384, 256, 0, stream>>>(ctxb, wob, bo, out,
                                      nullptr, nullptr, nullptr);
}